// Round 5
// baseline (191.184 us; speedup 1.0000x reference)
//
#include <hip/hip_runtime.h>
#include <hip/hip_fp16.h>
#include <cstddef>

#define N_ 1024
#define M_ 1024
#define D_ 1024
#define G_ 16
#define DG_ 64

typedef __bf16 bf16x8 __attribute__((ext_vector_type(8)));
typedef _Float16 f16x8 __attribute__((ext_vector_type(8)));
typedef float f32x4 __attribute__((ext_vector_type(4)));

// ---------------------------------------------------------------------------
// Weight prep: z=0/1 transpose-cast Wq/Wk -> [go][d] bf16; z=2 cast Wv (already
// [go][d]) -> bf16. 64x64 tiles.
// ---------------------------------------------------------------------------
__global__ __launch_bounds__(256)
void prep_weights(const float* __restrict__ Wq, const float* __restrict__ Wk,
                  const float* __restrict__ Wv,
                  __bf16* __restrict__ WqT, __bf16* __restrict__ WkT,
                  __bf16* __restrict__ Wvb)
{
    const int z = blockIdx.z;
    const int i0 = blockIdx.x * 64, j0 = blockIdx.y * 64;
    const int tid = threadIdx.x;
    const int r = tid >> 4, c4 = (tid & 15) * 4;

    if (z == 2) {
        #pragma unroll
        for (int it = 0; it < 4; ++it) {
            const int row = r + it * 16;
            float4 a = *(const float4*)&Wv[(size_t)(i0 + row) * D_ + j0 + c4];
            __bf16 p[4] = {(__bf16)a.x, (__bf16)a.y, (__bf16)a.z, (__bf16)a.w};
            *(uint2*)&Wvb[(size_t)(i0 + row) * D_ + j0 + c4] = *(const uint2*)p;
        }
        return;
    }

    __shared__ float t[64][65];
    const float* src = z ? Wk : Wq;
    __bf16* dst = z ? WkT : WqT;
    #pragma unroll
    for (int it = 0; it < 4; ++it) {
        float4 a = *(const float4*)&src[(size_t)(i0 + r + it * 16) * D_ + j0 + c4];
        t[r + it * 16][c4 + 0] = a.x; t[r + it * 16][c4 + 1] = a.y;
        t[r + it * 16][c4 + 2] = a.z; t[r + it * 16][c4 + 3] = a.w;
    }
    __syncthreads();
    #pragma unroll
    for (int it = 0; it < 4; ++it) {
        const int row = r + it * 16;
        __bf16 p[4];
        #pragma unroll
        for (int q = 0; q < 4; ++q) p[q] = (__bf16)t[c4 + q][row];
        *(uint2*)&dst[(size_t)(j0 + row) * D_ + i0 + c4] = *(const uint2*)p;
    }
}

// ---------------------------------------------------------------------------
// Fused MFMA GEMM, 128x128 tile, BK=64, double-buffered LDS, LDS-transpose
// epilogue with coalesced 16B stores.
// z=0: q[n][go] = bf16((roi@Wq + bq)*0.125)
// z=1: k[m][go] = bf16(ref@Wk + bk)
// z=2: Vt[go][m] = bf16(ref@Wv^T)
// ---------------------------------------------------------------------------
#define GP 72          // LDS pitch for staging tiles (bf16 elems)
#define CTP 136        // LDS pitch for epilogue tile

__global__ __launch_bounds__(256, 1)
void gemm_mfma(const float* __restrict__ roi, const float* __restrict__ ref,
               const __bf16* __restrict__ WqT, const __bf16* __restrict__ WkT,
               const __bf16* __restrict__ Wvb,
               const float* __restrict__ bq, const float* __restrict__ bk,
               __bf16* __restrict__ qout, __bf16* __restrict__ kout,
               __bf16* __restrict__ Vt)
{
    __shared__ __align__(16) char smem[2 * 2 * 128 * GP * 2];   // 73728 B

    const int z = blockIdx.z;
    const float* A = (z == 0) ? roi : ref;
    const __bf16* B = (z == 0) ? WqT : (z == 1) ? WkT : Wvb;
    const int tid = threadIdx.x;
    const int i0 = blockIdx.x * 128, j0 = blockIdx.y * 128;
    const int w = tid >> 6, lane = tid & 63;
    const int quad = lane >> 4, l15 = lane & 15;
    const int iw = (w & 1) * 64, jw = (w >> 1) * 64;

    const int arow = tid >> 4, ac = (tid & 15) * 4;   // A staging: 8 iters
    const int brow = tid >> 3, bc = (tid & 7) * 8;    // B staging: 4 iters

    f32x4 acc[4][4] = {};
    float4 ra[8];
    uint4 rb[4];

    auto As = [&](int buf) { return (__bf16(*)[GP])(smem + buf * 36864); };
    auto Bs = [&](int buf) { return (__bf16(*)[GP])(smem + buf * 36864 + 18432); };

    auto load_tile = [&](int kt) {
        const int k0 = kt * 64;
        #pragma unroll
        for (int it = 0; it < 8; ++it)
            ra[it] = *(const float4*)&A[(size_t)(i0 + arow + it * 16) * D_ + k0 + ac];
        #pragma unroll
        for (int it = 0; it < 4; ++it)
            rb[it] = *(const uint4*)&B[(size_t)(j0 + brow + it * 32) * D_ + k0 + bc];
    };
    auto write_tile = [&](int buf) {
        __bf16(*as)[GP] = As(buf);
        __bf16(*bs)[GP] = Bs(buf);
        #pragma unroll
        for (int it = 0; it < 8; ++it) {
            __bf16 p[4] = {(__bf16)ra[it].x, (__bf16)ra[it].y,
                           (__bf16)ra[it].z, (__bf16)ra[it].w};
            *(uint2*)&as[arow + it * 16][ac] = *(const uint2*)p;
        }
        #pragma unroll
        for (int it = 0; it < 4; ++it)
            *(uint4*)&bs[brow + it * 32][bc] = rb[it];
    };

    load_tile(0);
    write_tile(0);
    __syncthreads();

    for (int kt = 0; kt < 16; ++kt) {
        const int buf = kt & 1;
        if (kt < 15) load_tile(kt + 1);

        __bf16(*as)[GP] = As(buf);
        __bf16(*bs)[GP] = Bs(buf);
        #pragma unroll
        for (int ks = 0; ks < 2; ++ks) {
            bf16x8 af[4], bfr[4];
            #pragma unroll
            for (int t = 0; t < 4; ++t) {
                af[t]  = *(const bf16x8*)&as[iw + t * 16 + l15][ks * 32 + quad * 8];
                bfr[t] = *(const bf16x8*)&bs[jw + t * 16 + l15][ks * 32 + quad * 8];
            }
            #pragma unroll
            for (int ti = 0; ti < 4; ++ti)
                #pragma unroll
                for (int tj = 0; tj < 4; ++tj)
                    acc[ti][tj] = __builtin_amdgcn_mfma_f32_16x16x32_bf16(
                        af[ti], bfr[tj], acc[ti][tj], 0, 0, 0);
        }

        if (kt < 15) write_tile(buf ^ 1);
        __syncthreads();
    }

    // ---- epilogue: stage to LDS in output orientation, then coalesced copy ----
    __bf16(*Ct)[CTP] = (__bf16(*)[CTP])smem;   // 128 x 136 x 2B = 34816 B

    if (z < 2) {
        const float* bias = (z == 0) ? bq : bk;
        const float scale = (z == 0) ? 0.125f : 1.0f;
        // Ct[row = n-local][col = go-local]
        #pragma unroll
        for (int ti = 0; ti < 4; ++ti)
            #pragma unroll
            for (int tj = 0; tj < 4; ++tj) {
                const int col = jw + tj * 16 + l15;
                const float bb = bias[j0 + col];
                #pragma unroll
                for (int r = 0; r < 4; ++r)
                    Ct[iw + ti * 16 + quad * 4 + r][col] =
                        (__bf16)((acc[ti][tj][r] + bb) * scale);
            }
    } else {
        // Ct[row = go-local][col = m-local]  (transposed store, uint2 per lane)
        #pragma unroll
        for (int ti = 0; ti < 4; ++ti)
            #pragma unroll
            for (int tj = 0; tj < 4; ++tj) {
                const int col = jw + tj * 16 + l15;        // go-local
                const int row0 = iw + ti * 16 + quad * 4;  // m-local
                __bf16 p[4];
                #pragma unroll
                for (int r = 0; r < 4; ++r) p[r] = (__bf16)acc[ti][tj][r];
                *(uint2*)&Ct[col][row0] = *(const uint2*)p;
            }
    }
    __syncthreads();

    __bf16* dst = (z == 0) ? qout : (z == 1) ? kout : Vt;
    const int orow = tid >> 1, ohalf = (tid & 1) * 64;
    __bf16* gp = dst + (size_t)((z < 2 ? i0 : j0) + orow) * 1024 +
                 (z < 2 ? j0 : i0) + ohalf;
    #pragma unroll
    for (int c = 0; c < 8; ++c)
        *(uint4*)&gp[c * 8] = *(const uint4*)&Ct[orow][ohalf + c * 8];
}

// ---------------------------------------------------------------------------
// Positional affinity via MFMA f16 -> aw[g][n][m] fp16, 128B-chunk stores
// via wave-private LDS tile.
// ---------------------------------------------------------------------------
__global__ __launch_bounds__(256)
void posbias_mfma(const float* __restrict__ rois1, const float* __restrict__ rois2,
                  const float* __restrict__ Wg, const float* __restrict__ bg,
                  __half* __restrict__ aw)
{
    __shared__ __half pt[4][16][72];

    const int tid = threadIdx.x;
    const int w = tid >> 6, lane = tid & 63;
    const int quad = lane >> 4, l15 = lane & 15;
    const int n = blockIdx.y;
    const int m0w = blockIdx.x * 256 + w * 64;

    const float xmin = rois1[n * 4 + 0], ymin = rois1[n * 4 + 1];
    const float xmax = rois1[n * 4 + 2], ymax = rois1[n * 4 + 3];
    const float wn  = xmax - xmin + 1.f, hn  = ymax - ymin + 1.f;
    const float cxn = 0.5f * (xmin + xmax), cyn = 0.5f * (ymin + ymax);

    f16x8 wgf[2];
    #pragma unroll
    for (int ks = 0; ks < 2; ++ks) {
        const float* p = &Wg[l15 * 64 + ks * 32 + quad * 8];
        float4 a = *(const float4*)p;
        float4 b = *(const float4*)(p + 4);
        wgf[ks][0] = (_Float16)a.x; wgf[ks][1] = (_Float16)a.y;
        wgf[ks][2] = (_Float16)a.z; wgf[ks][3] = (_Float16)a.w;
        wgf[ks][4] = (_Float16)b.x; wgf[ks][5] = (_Float16)b.y;
        wgf[ks][6] = (_Float16)b.z; wgf[ks][7] = (_Float16)b.w;
    }
    const float bgv = bg[l15];

    const float fr8[8] = {100.0f, 42.16965f, 17.782794f, 7.4989421f,
                          3.1622777f, 1.3335214f, 0.56234133f, 0.23713737f};
    const float phase = (quad & 1) ? 1.5707963267948966f : 0.f;

    #pragma unroll
    for (int ti = 0; ti < 4; ++ti) {
        const int mt0 = m0w + ti * 16;
        const int m = mt0 + l15;
        float4 r2 = *(const float4*)&rois2[m * 4];
        const float wr  = r2.z - r2.x + 1.f, hr  = r2.w - r2.y + 1.f;
        const float cxr = 0.5f * (r2.x + r2.z), cyr = 0.5f * (r2.y + r2.w);

        const float f0 = __logf(fabsf((cxn - cxr) / wn) + 0.001f);
        const float f1 = __logf(fabsf((cyn - cyr) / hn) + 0.001f);
        const float f2 = __logf(wn / wr);
        const float f3 = __logf(hn / hr);
        const float fa = (quad & 2) ? f1 : f0;
        const float fb = (quad & 2) ? f3 : f2;

        f32x4 acc = {};
        #pragma unroll
        for (int ks = 0; ks < 2; ++ks) {
            const float feat = ks ? fb : fa;
            f16x8 ef;
            #pragma unroll
            for (int j = 0; j < 8; ++j)
                ef[j] = (_Float16)__sinf(fmaf(feat, fr8[j], phase));
            acc = __builtin_amdgcn_mfma_f32_16x16x32_f16(ef, wgf[ks], acc, 0, 0, 0);
        }

        // lane: group g = l15, m = mt0 + quad*4 + r  -> wave-private LDS
        __half p[4];
        #pragma unroll
        for (int r = 0; r < 4; ++r)
            p[r] = __float2half(fmaxf(acc[r] + bgv, 0.f) + 1e-6f);
        *(uint2*)&pt[w][l15][ti * 16 + quad * 4] = *(const uint2*)p;
    }

    // wave-private readout: lane -> (g = lane>>2, 16-m segment = lane&3)
    const int gg = lane >> 2, mseg = (lane & 3) * 16;
    __half* dst = aw + (size_t)gg * N_ * M_ + (size_t)n * M_ + m0w + mseg;
    *(uint4*)&dst[0] = *(const uint4*)&pt[w][gg][mseg];
    *(uint4*)&dst[8] = *(const uint4*)&pt[w][gg][mseg + 8];
}

// ---------------------------------------------------------------------------
// Wave-autonomous MFMA attention, row-major inputs. Block = (16-n band, g);
// each wave owns a 256-m chunk (no barriers in the m-loop); LDS combine.
// S^T = K q^T ; p = aw*exp(s) ; outT += V^T P^T.
// ---------------------------------------------------------------------------
__global__ __launch_bounds__(256)
void attn_mfma(const __bf16* __restrict__ qb, const __bf16* __restrict__ kb,
               const __bf16* __restrict__ Vt, const __half* __restrict__ aw,
               const float* __restrict__ bv, float* __restrict__ out)
{
    __shared__ __bf16 Ps[4][2][16][72];   // [wave][buf][n][m-of-64]
    __shared__ float accb[4][64][17];     // [wave][o][n]
    __shared__ float lsb[4][16];

    const int tid = threadIdx.x;
    const int w = tid >> 6, lane = tid & 63;
    const int quad = lane >> 4, l15 = lane & 15;
    const int nb = blockIdx.x, n0 = nb * 16, g = blockIdx.y;

    // q b-fragment: B[k=go][col=n=l15], straight from row-major q
    bf16x8 qf[2];
    qf[0] = *(const bf16x8*)&qb[(size_t)(n0 + l15) * D_ + g * 64 + quad * 8];
    qf[1] = *(const bf16x8*)&qb[(size_t)(n0 + l15) * D_ + g * 64 + 32 + quad * 8];

    f32x4 acc[4] = {};
    float llocal = 0.f;

    #pragma unroll
    for (int t64 = 0; t64 < 4; ++t64) {
        const int mt = w * 4 + t64;          // 64-m tile (0..15)
        const int m0 = mt * 64;
        const int buf = t64 & 1;

        // S^T: a-frag = K rows m, k = go
        f32x4 s[4];
        #pragma unroll
        for (int t = 0; t < 4; ++t) {
            const __bf16* kr = &kb[(size_t)(m0 + t * 16 + l15) * D_ + g * 64 + quad * 8];
            bf16x8 ka0 = *(const bf16x8*)kr;
            bf16x8 ka1 = *(const bf16x8*)(kr + 32);
            f32x4 zz = {};
            zz = __builtin_amdgcn_mfma_f32_16x16x32_bf16(ka0, qf[0], zz, 0, 0, 0);
            s[t] = __builtin_amdgcn_mfma_f32_16x16x32_bf16(ka1, qf[1], zz, 0, 0, 0);
        }

        // p = aw * exp(s): lane holds m = t*16 + quad*4 + r, n = l15
        #pragma unroll
        for (int t = 0; t < 4; ++t) {
            uint2 au = *(const uint2*)&aw[((size_t)g * N_ + n0 + l15) * M_ +
                                          m0 + t * 16 + quad * 4];
            const __half* a4 = (const __half*)&au;
            __bf16 pk[4];
            #pragma unroll
            for (int r = 0; r < 4; ++r) {
                const float p = __half2float(a4[r]) * __expf(s[t][r]);
                llocal += p;
                pk[r] = (__bf16)p;
            }
            *(uint2*)&Ps[w][buf][l15][t * 16 + quad * 4] = *(const uint2*)pk;
        }

        // outT += V^T P^T : a-frag = V rows o (k=m), b-frag = P cols n
        #pragma unroll
        for (int mcl = 0; mcl < 2; ++mcl) {
            bf16x8 pb = *(const bf16x8*)&Ps[w][buf][l15][mcl * 32 + quad * 8];
            #pragma unroll
            for (int ot = 0; ot < 4; ++ot) {
                bf16x8 va = *(const bf16x8*)&Vt[(size_t)(g * 64 + ot * 16 + l15) * M_ +
                                                m0 + mcl * 32 + quad * 8];
                acc[ot] = __builtin_amdgcn_mfma_f32_16x16x32_bf16(va, pb, acc[ot], 0, 0, 0);
            }
        }
    }

    // reduce l over lane bits 4,5 -> per n = l15
    llocal += __shfl_xor(llocal, 16, 64);
    llocal += __shfl_xor(llocal, 32, 64);

    #pragma unroll
    for (int ot = 0; ot < 4; ++ot)
        #pragma unroll
        for (int r = 0; r < 4; ++r)
            accb[w][ot * 16 + quad * 4 + r][l15] = acc[ot][r];
    if (quad == 0) lsb[w][l15] = llocal;
    __syncthreads();

    const float lt = lsb[0][l15] + lsb[1][l15] + lsb[2][l15] + lsb[3][l15];
    const float inv = 1.f / lt;
    #pragma unroll
    for (int r = 0; r < 4; ++r) {
        const int o = w * 16 + quad * 4 + r;
        const int ogl = g * 64 + o;
        const float v = accb[0][o][l15] + accb[1][o][l15] +
                        accb[2][o][l15] + accb[3][o][l15];
        out[(size_t)(n0 + l15) * D_ + ogl] = v * inv + bv[ogl];
    }
}

extern "C" void kernel_launch(void* const* d_in, const int* in_sizes, int n_in,
                              void* d_out, int out_size, void* d_ws, size_t ws_size,
                              hipStream_t stream) {
    const float* roi_feat = (const float*)d_in[0];
    const float* ref_feat = (const float*)d_in[1];
    const float* rois1    = (const float*)d_in[2];
    const float* rois2    = (const float*)d_in[3];
    const float* Wq       = (const float*)d_in[4];
    const float* bq       = (const float*)d_in[5];
    const float* Wk       = (const float*)d_in[6];
    const float* bk       = (const float*)d_in[7];
    const float* Wg       = (const float*)d_in[8];
    const float* bg       = (const float*)d_in[9];
    const float* Wv       = (const float*)d_in[10];
    const float* bv       = (const float*)d_in[11];
    float* out = (float*)d_out;

    char* ws = (char*)d_ws;
    __bf16* WqT  = (__bf16*)(ws + 0);
    __bf16* WkT  = (__bf16*)(ws + (2u << 20));
    __bf16* Wvb  = (__bf16*)(ws + (4u << 20));
    __bf16* qbuf = (__bf16*)(ws + (6u << 20));
    __bf16* kbuf = (__bf16*)(ws + (8u << 20));
    __bf16* Vtb  = (__bf16*)(ws + (10u << 20));
    __half* aw   = (__half*)(ws + (12u << 20));

    dim3 blk(256);
    prep_weights<<<dim3(16, 16, 3), blk, 0, stream>>>(Wq, Wk, Wv, WqT, WkT, Wvb);
    posbias_mfma<<<dim3(4, 1024), blk, 0, stream>>>(rois1, rois2, Wg, bg, aw);
    gemm_mfma<<<dim3(8, 8, 3), blk, 0, stream>>>(roi_feat, ref_feat, WqT, WkT, Wvb,
                                                 bq, bk, qbuf, kbuf, Vtb);
    attn_mfma<<<dim3(64, 16), blk, 0, stream>>>(qbuf, kbuf, Vtb, aw, bv, out);
}